// Round 1
// baseline (484.408 us; speedup 1.0000x reference)
//
#include <hip/hip_runtime.h>
#include <hip/hip_bf16.h>

// AttnBlock2D: B=4, C_IN=C_HID=512, H=W=64, N=4096.
//   k=Wk x+bk; q=Wq x+bq; v=Wv x+bv   (1x1 conv = per-pixel GEMM)
//   S[i,j] = <k_i, q_j>/sqrt(512); P = softmax_j(S); out[c,i] = sum_j P[i,j] v[c,j]
//   final = Wo out + bo
// Flash roles: Q_flash=k (i rows), K_flash=q (j rows), V_flash=v.
//
// All MFMA in bf16 (tolerance = 2% of absmax -> ample). f32 accumulate.

typedef __attribute__((ext_vector_type(4))) float f32x4;
typedef __attribute__((ext_vector_type(8))) short short8;
typedef __attribute__((ext_vector_type(4))) short short4v;

#define QSCALE 0.06376639774f   // (1/sqrt(512)) * log2(e): fold into k_t so exp2f works

__device__ __forceinline__ unsigned short f2bf(float f) {
  unsigned u = __builtin_bit_cast(unsigned, f);
  unsigned r = (u + 0x7FFFu + ((u >> 16) & 1u)) >> 16;   // RNE
  return (unsigned short)r;
}

__device__ __forceinline__ void gll16(const void* g, void* l) {
  // async global->LDS, 16B/lane; LDS dest = wave-uniform base + lane*16 (m104)
  __builtin_amdgcn_global_load_lds((const __attribute__((address_space(1))) void*)g,
                                   (__attribute__((address_space(3))) void*)l, 16, 0, 0);
}

// ---------------------------------------------------------------- cvt weights
__global__ __launch_bounds__(256) void cvt_w_kernel(
    const float* __restrict__ wk, const float* __restrict__ wq,
    const float* __restrict__ wv, const float* __restrict__ wo,
    short* __restrict__ o) {
  int z = blockIdx.y;
  const float* s = (z == 0) ? wk : (z == 1) ? wq : (z == 2) ? wv : wo;
  int i = blockIdx.x * 256 + threadIdx.x;          // 65536 float4 groups
  float4 f = ((const float4*)s)[i];
  short4v v;
  v[0] = (short)f2bf(f.x); v[1] = (short)f2bf(f.y);
  v[2] = (short)f2bf(f.z); v[3] = (short)f2bf(f.w);
  *(short4v*)(o + z * 262144 + i * 4) = v;
}

// --------------------------------------------------- transpose inp -> x_t bf16
// inp [b][c][n] f32  ->  x_t [(b,n)][c] bf16
__global__ __launch_bounds__(256) void transpose_x_kernel(
    const float* __restrict__ inp, short* __restrict__ xt) {
  __shared__ float t[32][33];
  int tx = threadIdx.x, ty = threadIdx.y;
  int n0 = blockIdx.x * 32, c0 = blockIdx.y * 32, b = blockIdx.z;
  const float* src = inp + ((size_t)(b * 512 + c0)) * 4096 + n0;
#pragma unroll
  for (int r = 0; r < 4; ++r) t[ty + r * 8][tx] = src[(ty + r * 8) * 4096 + tx];
  __syncthreads();
  short* dst = xt + ((size_t)((b << 12) + n0)) * 512 + c0;
#pragma unroll
  for (int r = 0; r < 4; ++r) dst[(ty + r * 8) * 512 + tx] = (short)f2bf(t[tx][ty + r * 8]);
}

// ------------------------------------------------------------- QKV projection
// z=0: k_t[n][o] = (x.Wk + bk)*QSCALE   z=1: q_t[n][o] = x.Wq + bq
// z=2: v_c[b][o][n] = x.Wv + bv  (channel-major; operands swapped)
// 128x128 tile, BK=32, 4 waves each 64x64. LDS rows 64B, XOR-swizzled by (row&3).
__global__ __launch_bounds__(256) void gemm_kqv_kernel(
    const short* __restrict__ xt,
    const short* __restrict__ wk, const short* __restrict__ wq, const short* __restrict__ wv,
    const float* __restrict__ bk, const float* __restrict__ bq, const float* __restrict__ bv,
    short* __restrict__ kt, short* __restrict__ qt, short* __restrict__ vc) {
  const int z = blockIdx.z;
  __shared__ short lds[2][128 * 32];
  const int tid = threadIdx.x, w = tid >> 6, lane = tid & 63;
  const int g = lane >> 4, l15 = lane & 15;
  int mt, nt;
  const short *Asrc, *Bsrc;
  if (z < 2) { mt = blockIdx.x; nt = blockIdx.y; Asrc = xt; Bsrc = (z == 0) ? wk : wq; }
  else       { mt = blockIdx.y; nt = blockIdx.x; Asrc = wv; Bsrc = xt; }
  const int arow0 = mt * 128, brow0 = nt * 128;
  const int wr = w >> 1, wc = w & 1;
  f32x4 acc[4][4] = {};
  const int rsub = lane >> 2, slot = lane & 3;
  for (int ki = 0; ki < 16; ++ki) {
    const int k0 = ki * 32;
    __syncthreads();
#pragma unroll
    for (int q = 0; q < 2; ++q) {
      int qq = w * 2 + q;
      int row = qq * 16 + rsub;
      int soff = ((slot ^ (row & 3)) * 16);
      gll16((const char*)(Asrc + (arow0 + row) * 512 + k0) + soff, (char*)&lds[0][0] + qq * 1024);
      gll16((const char*)(Bsrc + (brow0 + row) * 512 + k0) + soff, (char*)&lds[1][0] + qq * 1024);
    }
    __syncthreads();
    short8 am[4], bn[4];
#pragma unroll
    for (int m = 0; m < 4; ++m) {
      int row = wr * 64 + m * 16 + l15;
      am[m] = *(const short8*)((const char*)&lds[0][0] + row * 64 + ((g * 16) ^ ((l15 & 3) << 4)));
    }
#pragma unroll
    for (int n = 0; n < 4; ++n) {
      int row = wc * 64 + n * 16 + l15;
      bn[n] = *(const short8*)((const char*)&lds[1][0] + row * 64 + ((g * 16) ^ ((l15 & 3) << 4)));
    }
#pragma unroll
    for (int m = 0; m < 4; ++m)
#pragma unroll
      for (int n = 0; n < 4; ++n)
        acc[m][n] = __builtin_amdgcn_mfma_f32_16x16x32_bf16(am[m], bn[n], acc[m][n], 0, 0, 0);
  }
  // epilogue: D[row=4g+r][col=l15] per frag (m89 layout)
#pragma unroll
  for (int m = 0; m < 4; ++m) {
    int rA = arow0 + wr * 64 + m * 16 + g * 4;
#pragma unroll
    for (int n = 0; n < 4; ++n) {
      int cB = brow0 + wc * 64 + n * 16 + l15;
#pragma unroll
      for (int r = 0; r < 4; ++r) {
        float v = acc[m][n][r];
        int row = rA + r;
        if (z == 0)      kt[row * 512 + cB] = (short)f2bf((v + bk[cB]) * QSCALE);
        else if (z == 1) qt[row * 512 + cB] = (short)f2bf(v + bq[cB]);
        else {
          int bb = cB >> 12, nn = cB & 4095;
          vc[((size_t)((bb << 9) + row)) * 4096 + nn] = (short)f2bf(v + bv[row]);
        }
      }
    }
  }
}

// ----------------------------------------------------------- flash attention
// grid 256 blocks (XCD-mapped: batch b -> XCDs {2b,2b+1}); 4 waves x 16 i-rows
// j-tile 32, double-buffered K/V LDS staging, Q in regs, online softmax+defer-max.
// LDS: K[2][32][512] (rows 1KB, XOR swz (j&7)<<4) | V[2][512][32] (rows 64B,
// XOR swz ((c>>1)&3)<<4) | P per wave [16][40] bf16.
__global__ __launch_bounds__(256) void attn_kernel(
    const short* __restrict__ kt, const short* __restrict__ qt,
    const short* __restrict__ vc, short* __restrict__ outt) {
  extern __shared__ char smem[];
  const int tid = threadIdx.x, w = tid >> 6, lane = tid & 63;
  const int g = lane >> 4, l15 = lane & 15;
  const int r8 = blockIdx.x & 7, h = blockIdx.x >> 3;
  const int b = r8 >> 1;
  const int i0 = (h * 2 + (r8 & 1)) * 64;

  // Q (=k_t, pre-scaled) in regs: A-frag row=l15, k=g*8+e
  short8 qf[16];
  {
    const short* qbase = kt + ((size_t)((b << 12) + i0 + w * 16 + l15)) * 512;
#pragma unroll
    for (int kc = 0; kc < 16; ++kc) qf[kc] = *(const short8*)(qbase + kc * 32 + g * 8);
  }
  f32x4 of[32] = {};
  float m_[4] = {-3e38f, -3e38f, -3e38f, -3e38f};
  float l_[4] = {0.f, 0.f, 0.f, 0.f};
  char* Pw = smem + 131072 + w * 1280;

  auto stage = [&](int buf, int j0) {
    char* Kb = smem + buf * 32768;
    char* Vb = smem + 65536 + buf * 32768;
    const char* qtb = (const char*)(qt + ((size_t)((b << 12) + j0)) * 512);
#pragma unroll
    for (int q = 0; q < 8; ++q) {        // K: one row (1KB) per instr
      int jr = w * 8 + q;
      gll16(qtb + jr * 1024 + ((lane * 16) ^ ((jr & 7) << 4)), Kb + jr * 1024);
    }
#pragma unroll
    for (int q = 0; q < 8; ++q) {        // V: 16 rows (64B each) per instr
      int c0 = (w * 8 + q) * 16;
      int c = c0 + (lane >> 2);
      const char* src = (const char*)(vc + ((size_t)((b << 9) + c)) * 4096 + j0)
                        + (((lane & 3) ^ ((c >> 1) & 3)) * 16);
      gll16(src, Vb + c0 * 64);
    }
  };

  stage(0, 0);
  asm volatile("s_waitcnt vmcnt(0)" ::: "memory");
  __builtin_amdgcn_s_barrier();

  for (int jt = 0; jt < 128; ++jt) {
    const int buf = jt & 1;
    if (jt < 127) stage(buf ^ 1, (jt + 1) * 32);   // overlap with compute
    const char* Kb = smem + buf * 32768;
    const char* Vb = smem + 65536 + buf * 32768;

    // S = Q.K^T : D rows i=4g+r, cols j=jf*16+l15
    f32x4 sacc[2] = {};
#pragma unroll
    for (int kc = 0; kc < 16; ++kc) {
#pragma unroll
      for (int jf = 0; jf < 2; ++jf) {
        int jr = jf * 16 + l15;
        short8 kb = *(const short8*)(Kb + jr * 1024 + ((kc * 64 + g * 16) ^ ((jr & 7) << 4)));
        sacc[jf] = __builtin_amdgcn_mfma_f32_16x16x32_bf16(qf[kc], kb, sacc[jf], 0, 0, 0);
      }
    }

    // online softmax (logits already in log2 units)
    float pmax[4];
    bool need = false;
#pragma unroll
    for (int r = 0; r < 4; ++r) {
      float mx = fmaxf(sacc[0][r], sacc[1][r]);
      mx = fmaxf(mx, __shfl_xor(mx, 1)); mx = fmaxf(mx, __shfl_xor(mx, 2));
      mx = fmaxf(mx, __shfl_xor(mx, 4)); mx = fmaxf(mx, __shfl_xor(mx, 8));
      pmax[r] = mx;
      need = need || (mx > m_[r] + 8.0f);
    }
    if (__any((int)need)) {              // T13 defer-max: rescale only on growth
      float a_[4];
#pragma unroll
      for (int r = 0; r < 4; ++r) {
        float mn = fmaxf(m_[r], pmax[r]);
        a_[r] = exp2f(m_[r] - mn);
        m_[r] = mn;
        l_[r] *= a_[r];
      }
#pragma unroll
      for (int cf = 0; cf < 32; ++cf)
#pragma unroll
        for (int r = 0; r < 4; ++r) of[cf][r] *= a_[r];
    }
    float p0[4], p1[4];
#pragma unroll
    for (int r = 0; r < 4; ++r) {
      p0[r] = exp2f(sacc[0][r] - m_[r]);
      p1[r] = exp2f(sacc[1][r] - m_[r]);
      float s = p0[r] + p1[r];
      s += __shfl_xor(s, 1); s += __shfl_xor(s, 2);
      s += __shfl_xor(s, 4); s += __shfl_xor(s, 8);
      l_[r] += s;
    }
    // P -> per-wave LDS (row pitch 80B), reread as A-frag [row=i][k=j]
#pragma unroll
    for (int r = 0; r < 4; ++r) {
      *(short*)(Pw + (g * 4 + r) * 80 + l15 * 2)        = (short)f2bf(p0[r]);
      *(short*)(Pw + (g * 4 + r) * 80 + 32 + l15 * 2)   = (short)f2bf(p1[r]);
    }
    short8 pa = *(const short8*)(Pw + l15 * 80 + g * 16);
    // O += P.V : B[k=j][col=c] from V_lds[c][j]
#pragma unroll
    for (int cf = 0; cf < 32; ++cf) {
      int c = cf * 16 + l15;
      short8 vb = *(const short8*)(Vb + c * 64 + ((g * 16) ^ (((c >> 1) & 3) << 4)));
      of[cf] = __builtin_amdgcn_mfma_f32_16x16x32_bf16(pa, vb, of[cf], 0, 0, 0);
    }
    asm volatile("s_waitcnt vmcnt(0)" ::: "memory");
    __builtin_amdgcn_s_barrier();
  }

  // epilogue: out_t[(b,i)][c] = O/l
  short* ob = outt + ((size_t)((b << 12) + i0 + w * 16)) * 512;
#pragma unroll
  for (int r = 0; r < 4; ++r) {
    float inv = 1.0f / l_[r];
    int row = g * 4 + r;
#pragma unroll
    for (int cf = 0; cf < 32; ++cf)
      ob[row * 512 + cf * 16 + l15] = (short)f2bf(of[cf][r] * inv);
  }
}

// ------------------------------------------------------------ out projection
// final[b][co][n] = Wo.out_t + bo ; A=Wo[co][ch], B[k=ch][col=n]=out_t[n][ch]
__global__ __launch_bounds__(256) void gemm_out_kernel(
    const short* __restrict__ wo, const short* __restrict__ outt,
    const float* __restrict__ bo, float* __restrict__ out) {
  __shared__ short lds[2][128 * 32];
  const int tid = threadIdx.x, w = tid >> 6, lane = tid & 63;
  const int g = lane >> 4, l15 = lane & 15;
  const int bz = blockIdx.z;
  const int arow0 = blockIdx.y * 128;                 // co
  const int brow0 = (bz << 12) + blockIdx.x * 128;    // flattened (b,n)
  const int wr = w >> 1, wc = w & 1;
  f32x4 acc[4][4] = {};
  const int rsub = lane >> 2, slot = lane & 3;
  for (int ki = 0; ki < 16; ++ki) {
    const int k0 = ki * 32;
    __syncthreads();
#pragma unroll
    for (int q = 0; q < 2; ++q) {
      int qq = w * 2 + q;
      int row = qq * 16 + rsub;
      int soff = ((slot ^ (row & 3)) * 16);
      gll16((const char*)(wo + (arow0 + row) * 512 + k0) + soff, (char*)&lds[0][0] + qq * 1024);
      gll16((const char*)(outt + (size_t)(brow0 + row) * 512 + k0) + soff, (char*)&lds[1][0] + qq * 1024);
    }
    __syncthreads();
    short8 am[4], bn[4];
#pragma unroll
    for (int m = 0; m < 4; ++m) {
      int row = wr * 64 + m * 16 + l15;
      am[m] = *(const short8*)((const char*)&lds[0][0] + row * 64 + ((g * 16) ^ ((l15 & 3) << 4)));
    }
#pragma unroll
    for (int n = 0; n < 4; ++n) {
      int row = wc * 64 + n * 16 + l15;
      bn[n] = *(const short8*)((const char*)&lds[1][0] + row * 64 + ((g * 16) ^ ((l15 & 3) << 4)));
    }
#pragma unroll
    for (int m = 0; m < 4; ++m)
#pragma unroll
      for (int n = 0; n < 4; ++n)
        acc[m][n] = __builtin_amdgcn_mfma_f32_16x16x32_bf16(am[m], bn[n], acc[m][n], 0, 0, 0);
  }
#pragma unroll
  for (int m = 0; m < 4; ++m) {
    int co = arow0 + wr * 64 + m * 16 + g * 4;
#pragma unroll
    for (int n = 0; n < 4; ++n) {
      int nl = blockIdx.x * 128 + wc * 64 + n * 16 + l15;
#pragma unroll
      for (int r = 0; r < 4; ++r)
        out[((size_t)(bz * 512 + co + r) << 12) + nl] = acc[m][n][r] + bo[co + r];
    }
  }
}

// ---------------------------------------------------------------------- host
extern "C" void kernel_launch(void* const* d_in, const int* in_sizes, int n_in,
                              void* d_out, int out_size, void* d_ws, size_t ws_size,
                              hipStream_t stream) {
  const float* inp = (const float*)d_in[0];
  const float* Wk = (const float*)d_in[1];
  const float* bk = (const float*)d_in[2];
  const float* Wq = (const float*)d_in[3];
  const float* bq = (const float*)d_in[4];
  const float* Wv = (const float*)d_in[5];
  const float* bv = (const float*)d_in[6];
  const float* Wo = (const float*)d_in[7];
  const float* bo = (const float*)d_in[8];
  float* out = (float*)d_out;
  char* ws = (char*)d_ws;
  // ws layout (86 MB): xt | kt | qt | vc | out_t | weights(bf16)
  short* xt = (short*)(ws);
  short* kt = (short*)(ws + 1 * 16777216);
  short* qt = (short*)(ws + 2 * 16777216);
  short* vc = (short*)(ws + 3 * 16777216);
  short* ot = (short*)(ws + 4 * 16777216);
  short* wb = (short*)(ws + 5 * 16777216);

  (void)in_sizes; (void)n_in; (void)out_size; (void)ws_size;

  hipFuncSetAttribute((const void*)attn_kernel,
                      hipFuncAttributeMaxDynamicSharedMemorySize, 136192);

  cvt_w_kernel<<<dim3(256, 4), 256, 0, stream>>>(Wk, Wq, Wv, Wo, wb);
  transpose_x_kernel<<<dim3(128, 16, 4), dim3(32, 8, 1), 0, stream>>>(inp, xt);
  gemm_kqv_kernel<<<dim3(128, 4, 3), 256, 0, stream>>>(
      xt, wb, wb + 262144, wb + 524288, bk, bq, bv, kt, qt, vc);
  attn_kernel<<<dim3(256), dim3(256), 136192, stream>>>(kt, qt, vc, ot);
  gemm_out_kernel<<<dim3(32, 4, 4), 256, 0, stream>>>(wb + 786432, ot, bo, out);
}

// Round 2
// 364.887 us; speedup vs baseline: 1.3276x; 1.3276x over previous
//
#include <hip/hip_runtime.h>
#include <hip/hip_bf16.h>

// AttnBlock2D decoupled-GEMM pipeline. B=4, C=512, N=4096 per batch.
//   kt[(b,i)][c] = (x.Wk + bk) * (log2e/sqrt(512))   (flash-Q, log2 units)
//   qt[(b,j)][c] = x.Wq + bq                          (flash-K)
//   vc[c][(b,j)] = x.Wv + bv                          (channel-major V)
//   P[b][i][j] = exp2(kt.qt^T)          (UNNORMALIZED; logits bounded -> safe)
//   l[b][i] = sum_j P  -> linv = 1/l    (factors out to final epilogue)
//   o32[(b,i)][c] = P.V  (f32)  -> ot bf16
//   out[b][co][n] = (Wo.ot^T) * linv[n] + bo
// All GEMMs share one verified 128^2/BK=32 core (A[row][k] x B^T[col][k]).

typedef __attribute__((ext_vector_type(4))) float f32x4;
typedef __attribute__((ext_vector_type(8))) short short8;
typedef __attribute__((ext_vector_type(4))) short short4v;

#define QSCALE 0.06376639774f   // (1/sqrt(512)) * log2(e)

__device__ __forceinline__ unsigned short f2bf(float f) {
  unsigned u = __builtin_bit_cast(unsigned, f);
  unsigned r = (u + 0x7FFFu + ((u >> 16) & 1u)) >> 16;   // RNE
  return (unsigned short)r;
}

__device__ __forceinline__ void gll16(const void* g, void* l) {
  __builtin_amdgcn_global_load_lds((const __attribute__((address_space(1))) void*)g,
                                   (__attribute__((address_space(3))) void*)l, 16, 0, 0);
}

// ------------------------------------------------------------ shared GEMM core
// C[128x128] tile = A[128 x 32k-steps] . B^T ; A rows stride lda (shorts),
// B rows stride ldb. 4 waves, each 64x64 (4x4 16x16x32 frags). Verified R1.
__device__ __forceinline__ void gemm_core(const short* __restrict__ A, int lda,
                                          const short* __restrict__ B, int ldb,
                                          int nk, short* lds, f32x4 (&acc)[4][4]) {
  const int tid = threadIdx.x, w = tid >> 6, lane = tid & 63;
  const int g = lane >> 4, l15 = lane & 15;
  const int wr = w >> 1, wc = w & 1;
  const int rsub = lane >> 2, slot = lane & 3;
  char* la = (char*)lds;
  char* lb = (char*)(lds + 128 * 32);
  for (int ki = 0; ki < nk; ++ki) {
    const int k0 = ki * 32;
    __syncthreads();
#pragma unroll
    for (int q = 0; q < 2; ++q) {
      int qq = w * 2 + q;
      int row = qq * 16 + rsub;
      int soff = ((slot ^ (row & 3)) * 16);
      gll16((const char*)(A + (size_t)row * lda + k0) + soff, la + qq * 1024);
      gll16((const char*)(B + (size_t)row * ldb + k0) + soff, lb + qq * 1024);
    }
    __syncthreads();
    short8 am[4], bn[4];
#pragma unroll
    for (int m = 0; m < 4; ++m) {
      int row = wr * 64 + m * 16 + l15;
      am[m] = *(const short8*)(la + row * 64 + ((g * 16) ^ ((l15 & 3) << 4)));
    }
#pragma unroll
    for (int n = 0; n < 4; ++n) {
      int row = wc * 64 + n * 16 + l15;
      bn[n] = *(const short8*)(lb + row * 64 + ((g * 16) ^ ((l15 & 3) << 4)));
    }
#pragma unroll
    for (int m = 0; m < 4; ++m)
#pragma unroll
      for (int n = 0; n < 4; ++n)
        acc[m][n] = __builtin_amdgcn_mfma_f32_16x16x32_bf16(am[m], bn[n], acc[m][n], 0, 0, 0);
  }
}

// ---------------------------------------------------------------- cvt weights
__global__ __launch_bounds__(256) void cvt_w_kernel(
    const float* __restrict__ wk, const float* __restrict__ wq,
    const float* __restrict__ wv, const float* __restrict__ wo,
    short* __restrict__ o) {
  int z = blockIdx.y;
  const float* s = (z == 0) ? wk : (z == 1) ? wq : (z == 2) ? wv : wo;
  int i = blockIdx.x * 256 + threadIdx.x;
  float4 f = ((const float4*)s)[i];
  short4v v;
  v[0] = (short)f2bf(f.x); v[1] = (short)f2bf(f.y);
  v[2] = (short)f2bf(f.z); v[3] = (short)f2bf(f.w);
  *(short4v*)(o + z * 262144 + i * 4) = v;
}

// --------------------------------------------------- transpose inp -> x_t bf16
__global__ __launch_bounds__(256) void transpose_x_kernel(
    const float* __restrict__ inp, short* __restrict__ xt) {
  __shared__ float t[32][33];
  int tx = threadIdx.x, ty = threadIdx.y;
  int n0 = blockIdx.x * 32, c0 = blockIdx.y * 32, b = blockIdx.z;
  const float* src = inp + ((size_t)(b * 512 + c0)) * 4096 + n0;
#pragma unroll
  for (int r = 0; r < 4; ++r) t[ty + r * 8][tx] = src[(ty + r * 8) * 4096 + tx];
  __syncthreads();
  short* dst = xt + ((size_t)((b << 12) + n0)) * 512 + c0;
#pragma unroll
  for (int r = 0; r < 4; ++r) dst[(ty + r * 8) * 512 + tx] = (short)f2bf(t[tx][ty + r * 8]);
}

// ------------------------------------------------------------- QKV projection
__global__ __launch_bounds__(256) void gemm_kqv_kernel(
    const short* __restrict__ xt,
    const short* __restrict__ wk, const short* __restrict__ wq, const short* __restrict__ wv,
    const float* __restrict__ bk, const float* __restrict__ bq, const float* __restrict__ bv,
    short* __restrict__ kt, short* __restrict__ qt, short* __restrict__ vc) {
  const int z = blockIdx.z;
  __shared__ short lds[2 * 128 * 32];
  const short *A, *B;
  int arow0, brow0;
  if (z < 2) { arow0 = blockIdx.x * 128; brow0 = blockIdx.y * 128;
               A = xt + (size_t)arow0 * 512; B = ((z == 0) ? wk : wq) + (size_t)brow0 * 512; }
  else       { arow0 = blockIdx.y * 128; brow0 = blockIdx.x * 128;
               A = wv + (size_t)arow0 * 512; B = xt + (size_t)brow0 * 512; }
  f32x4 acc[4][4] = {};
  gemm_core(A, 512, B, 512, 16, lds, acc);
  const int tid = threadIdx.x, w = tid >> 6, lane = tid & 63;
  const int g = lane >> 4, l15 = lane & 15;
  const int wr = w >> 1, wc = w & 1;
#pragma unroll
  for (int m = 0; m < 4; ++m) {
    int rA = arow0 + wr * 64 + m * 16 + g * 4;
#pragma unroll
    for (int n = 0; n < 4; ++n) {
      int cB = brow0 + wc * 64 + n * 16 + l15;
#pragma unroll
      for (int r = 0; r < 4; ++r) {
        float v = acc[m][n][r];
        int row = rA + r;
        if (z == 0)      kt[(size_t)row * 512 + cB] = (short)f2bf((v + bk[cB]) * QSCALE);
        else if (z == 1) qt[(size_t)row * 512 + cB] = (short)f2bf(v + bq[cB]);
        else             vc[(size_t)row * 16384 + cB] = (short)f2bf(v + bv[row]);
      }
    }
  }
}

// ------------------------------------------------- S-GEMM + exp2 + row-partials
// P[b][i][jl] = exp2(kt . qt^T), Lpart[b][jp][i] = partial row sums (64-col gran)
__global__ __launch_bounds__(256) void gemm_s_kernel(
    const short* __restrict__ kt, const short* __restrict__ qt,
    short* __restrict__ P, float* __restrict__ Lpart, int j0, int jc) {
  __shared__ short lds[2 * 128 * 32];
  const int b = blockIdx.z, i0 = blockIdx.y * 128, jl0 = blockIdx.x * 128;
  const short* A = kt + ((size_t)(b << 12) + i0) * 512;
  const short* B = qt + ((size_t)(b << 12) + j0 + jl0) * 512;
  f32x4 acc[4][4] = {};
  gemm_core(A, 512, B, 512, 16, lds, acc);
  const int tid = threadIdx.x, w = tid >> 6, lane = tid & 63;
  const int g = lane >> 4, l15 = lane & 15;
  const int wr = w >> 1, wc = w & 1;
  short* Pb = P + ((size_t)(b << 12) + i0 + wr * 64) * jc + jl0 + wc * 64;
  float rs[4][4];
#pragma unroll
  for (int m = 0; m < 4; ++m)
#pragma unroll
    for (int r = 0; r < 4; ++r) rs[m][r] = 0.f;
#pragma unroll
  for (int m = 0; m < 4; ++m)
#pragma unroll
    for (int n = 0; n < 4; ++n)
#pragma unroll
      for (int r = 0; r < 4; ++r) {
        float p = exp2f(acc[m][n][r]);
        rs[m][r] += p;
        Pb[(size_t)(m * 16 + g * 4 + r) * jc + n * 16 + l15] = (short)f2bf(p);
      }
  const int jp = ((j0 + jl0) >> 6) + wc;
  float* Lp = Lpart + (((size_t)b * 64 + jp) << 12) + i0 + wr * 64;
#pragma unroll
  for (int m = 0; m < 4; ++m)
#pragma unroll
    for (int r = 0; r < 4; ++r) {
      float s = rs[m][r];
      s += __shfl_xor(s, 1); s += __shfl_xor(s, 2);
      s += __shfl_xor(s, 4); s += __shfl_xor(s, 8);
      if (l15 == 0) Lp[m * 16 + g * 4 + r] = s;
    }
}

// ------------------------------------------------------------------ PV-GEMM
// o32[(b,i)][c] (+)= P[b][i][:] . vc[c][(b,:)]^T
__global__ __launch_bounds__(256) void gemm_pv_kernel(
    const short* __restrict__ P, const short* __restrict__ vc,
    float* __restrict__ o32, int jc, int add) {
  __shared__ short lds[2 * 128 * 32];
  const int b = blockIdx.z, i0 = blockIdx.y * 128, c0 = blockIdx.x * 128;
  const short* A = P + ((size_t)(b << 12) + i0) * jc;
  const short* B = vc + (size_t)c0 * 16384 + (b << 12);
  f32x4 acc[4][4] = {};
  gemm_core(A, jc, B, 16384, jc >> 5, lds, acc);
  const int tid = threadIdx.x, w = tid >> 6, lane = tid & 63;
  const int g = lane >> 4, l15 = lane & 15;
  const int wr = w >> 1, wc = w & 1;
  float* ob = o32 + ((size_t)(b << 12) + i0 + wr * 64) * 512 + c0 + wc * 64;
#pragma unroll
  for (int m = 0; m < 4; ++m)
#pragma unroll
    for (int n = 0; n < 4; ++n)
#pragma unroll
      for (int r = 0; r < 4; ++r) {
        size_t idx = (size_t)(m * 16 + g * 4 + r) * 512 + n * 16 + l15;
        ob[idx] = acc[m][n][r] + (add ? ob[idx] : 0.f);
      }
}

// ------------------------------------------------------------------ l reduce
__global__ __launch_bounds__(256) void lred_kernel(
    const float* __restrict__ Lpart, float* __restrict__ linv) {
  int i = blockIdx.x * 256 + threadIdx.x;      // 16384 = (b,i)
  int b = i >> 12;
  float s = 0.f;
#pragma unroll 8
  for (int jp = 0; jp < 64; ++jp) s += Lpart[(((size_t)b * 64 + jp) << 12) + (i & 4095)];
  linv[i] = 1.0f / s;
}

// ------------------------------------------------------------------ o32 -> bf16
__global__ __launch_bounds__(256) void cvto_kernel(
    const float* __restrict__ o32, short* __restrict__ ot) {
  int i = blockIdx.x * 256 + threadIdx.x;      // x4 floats
  float4 f = ((const float4*)o32)[i];
  short4v v;
  v[0] = (short)f2bf(f.x); v[1] = (short)f2bf(f.y);
  v[2] = (short)f2bf(f.z); v[3] = (short)f2bf(f.w);
  ((short4v*)ot)[i] = v;
}

// ------------------------------------------------------------ final projection
// out[b][co][n] = (Wo . ot^T) * linv[(b,n)] + bo
__global__ __launch_bounds__(256) void gemm_out_kernel(
    const short* __restrict__ wo, const short* __restrict__ ot,
    const float* __restrict__ bo, const float* __restrict__ linv,
    float* __restrict__ out) {
  __shared__ short lds[2 * 128 * 32];
  const int b = blockIdx.z;
  const int arow0 = blockIdx.y * 128;                 // co
  const int bn0 = blockIdx.x * 128;                   // n within batch
  const short* A = wo + (size_t)arow0 * 512;
  const short* B = ot + ((size_t)(b << 12) + bn0) * 512;
  f32x4 acc[4][4] = {};
  gemm_core(A, 512, B, 512, 16, lds, acc);
  const int tid = threadIdx.x, w = tid >> 6, lane = tid & 63;
  const int g = lane >> 4, l15 = lane & 15;
  const int wr = w >> 1, wc = w & 1;
#pragma unroll
  for (int m = 0; m < 4; ++m) {
    int co = arow0 + wr * 64 + m * 16 + g * 4;
#pragma unroll
    for (int n = 0; n < 4; ++n) {
      int nl = bn0 + wc * 64 + n * 16 + l15;
      float li = linv[(b << 12) + nl];
#pragma unroll
      for (int r = 0; r < 4; ++r)
        out[((size_t)(b * 512 + co + r) << 12) + nl] = acc[m][n][r] * li + bo[co + r];
    }
  }
}

// ---------------------------------------------------------------------- host
extern "C" void kernel_launch(void* const* d_in, const int* in_sizes, int n_in,
                              void* d_out, int out_size, void* d_ws, size_t ws_size,
                              hipStream_t stream) {
  const float* inp = (const float*)d_in[0];
  const float* Wk = (const float*)d_in[1];
  const float* bk = (const float*)d_in[2];
  const float* Wq = (const float*)d_in[3];
  const float* bq = (const float*)d_in[4];
  const float* Wv = (const float*)d_in[5];
  const float* bv = (const float*)d_in[6];
  const float* Wo = (const float*)d_in[7];
  const float* bo = (const float*)d_in[8];
  float* out = (float*)d_out;
  char* ws = (char*)d_ws;
  const size_t MB = 1048576;
  // layout: kt16 | qt16 | vc16 | o32(f32)32 | ot16 | wb2 | Lpart4 | linv64K | xt16
  // P aliases xt (xt dead after QKV proj) and extends per chunk size.
  short* kt    = (short*)(ws);
  short* qt    = (short*)(ws + 16 * MB);
  short* vc    = (short*)(ws + 32 * MB);
  float* o32   = (float*)(ws + 48 * MB);
  short* ot    = (short*)(ws + 80 * MB);
  short* wb    = (short*)(ws + 96 * MB);
  float* Lpart = (float*)(ws + 98 * MB);
  float* linv  = (float*)(ws + 102 * MB);
  short* xt    = (short*)(ws + 102 * MB + 65536);
  short* P     = xt;                       // reuse region
  const size_t P_off = 102 * MB + 65536;

  (void)in_sizes; (void)n_in; (void)out_size;

  // chunk size over j for P materialization, fit to workspace
  int jc = (ws_size >= P_off + 128 * MB) ? 4096
         : (ws_size >= P_off + 32 * MB)  ? 1024 : 512;
  int nchunk = 4096 / jc;

  cvt_w_kernel<<<dim3(256, 4), 256, 0, stream>>>(Wk, Wq, Wv, Wo, wb);
  transpose_x_kernel<<<dim3(128, 16, 4), dim3(32, 8, 1), 0, stream>>>(inp, xt);
  gemm_kqv_kernel<<<dim3(128, 4, 3), 256, 0, stream>>>(
      xt, wb, wb + 262144, wb + 524288, bk, bq, bv, kt, qt, vc);
  for (int c = 0; c < nchunk; ++c) {
    gemm_s_kernel<<<dim3(jc / 128, 32, 4), 256, 0, stream>>>(kt, qt, P, Lpart, c * jc, jc);
    gemm_pv_kernel<<<dim3(4, 32, 4), 256, 0, stream>>>(P, vc, o32, jc, c);
  }
  lred_kernel<<<64, 256, 0, stream>>>(Lpart, linv);
  cvto_kernel<<<8192, 256, 0, stream>>>(o32, ot);
  gemm_out_kernel<<<dim3(32, 4, 4), 256, 0, stream>>>(wb + 786432, ot, bo, linv, out);
}

// Round 3
// 317.718 us; speedup vs baseline: 1.5246x; 1.1485x over previous
//
#include <hip/hip_runtime.h>
#include <hip/hip_bf16.h>

// AttnBlock2D decoupled-GEMM pipeline, R3. B=4, C=512, N=4096 per batch.
//   kt[(b,i)][c] = (x.Wk + bk) * (log2e/sqrt(512))   (log2-units flash-Q)
//   qt[(b,j)][c] = x.Wq + bq
//   vc[c][(b,j)] = x.Wv + bv                          (channel-major V)
//   P_h[b][i][jl] = exp2(kt.qt^T)  for j-half h       (UNNORMALIZED)
//   otab[(b,i)][h*512+c] = P_h.V   (bf16 partial halves, side by side)
//   out[b][co][n] = (Wo_dup . otab^T) * linv[(b,n)] + bo   (K=1024 folds halves)
// All GEMMs share the verified 128^2/BK=32 core. Epilogues bounce through a
// swizzled 32KB LDS tile for coalesced 16B stores.

typedef __attribute__((ext_vector_type(4))) float f32x4;
typedef __attribute__((ext_vector_type(8))) short short8;
typedef __attribute__((ext_vector_type(4))) short short4v;

#define QSCALE 0.06376639774f   // (1/sqrt(512)) * log2(e)

__device__ __forceinline__ unsigned short f2bf(float f) {
  unsigned u = __builtin_bit_cast(unsigned, f);
  unsigned r = (u + 0x7FFFu + ((u >> 16) & 1u)) >> 16;   // RNE
  return (unsigned short)r;
}

__device__ __forceinline__ void gll16(const void* g, void* l) {
  __builtin_amdgcn_global_load_lds((const __attribute__((address_space(1))) void*)g,
                                   (__attribute__((address_space(3))) void*)l, 16, 0, 0);
}

// ------------------------------------------------------------ shared GEMM core
// C[128x128] tile = A . B^T, BK=32, 4 waves each 64x64 (4x4 16x16x32 frags).
__device__ __forceinline__ void gemm_core(const short* __restrict__ A, int lda,
                                          const short* __restrict__ B, int ldb,
                                          int nk, short* lds, f32x4 (&acc)[4][4]) {
  const int tid = threadIdx.x, w = tid >> 6, lane = tid & 63;
  const int g = lane >> 4, l15 = lane & 15;
  const int wr = w >> 1, wc = w & 1;
  const int rsub = lane >> 2, slot = lane & 3;
  char* la = (char*)lds;
  char* lb = (char*)(lds + 128 * 32);
  for (int ki = 0; ki < nk; ++ki) {
    const int k0 = ki * 32;
    __syncthreads();
#pragma unroll
    for (int q = 0; q < 2; ++q) {
      int qq = w * 2 + q;
      int row = qq * 16 + rsub;
      int soff = ((slot ^ (row & 3)) * 16);
      gll16((const char*)(A + (size_t)row * lda + k0) + soff, la + qq * 1024);
      gll16((const char*)(B + (size_t)row * ldb + k0) + soff, lb + qq * 1024);
    }
    __syncthreads();
    short8 am[4], bn[4];
#pragma unroll
    for (int m = 0; m < 4; ++m) {
      int row = wr * 64 + m * 16 + l15;
      am[m] = *(const short8*)(la + row * 64 + ((g * 16) ^ ((l15 & 3) << 4)));
    }
#pragma unroll
    for (int n = 0; n < 4; ++n) {
      int row = wc * 64 + n * 16 + l15;
      bn[n] = *(const short8*)(lb + row * 64 + ((g * 16) ^ ((l15 & 3) << 4)));
    }
#pragma unroll
    for (int m = 0; m < 4; ++m)
#pragma unroll
      for (int n = 0; n < 4; ++n)
        acc[m][n] = __builtin_amdgcn_mfma_f32_16x16x32_bf16(am[m], bn[n], acc[m][n], 0, 0, 0);
  }
}

// bounce helpers: write-side swizzled scalar stores, read-side 16B coalesced.
#define BOUNCE_WRITE(lds2, row, col, val) \
  (lds2)[(row) * 128 + ((col) ^ (((row) & 7) << 3))] = (val)

#define BOUNCE_FLUSH(lds2, gbase, pitch)                                        \
  do {                                                                          \
    __syncthreads();                                                            \
    _Pragma("unroll")                                                           \
    for (int it_ = 0; it_ < 8; ++it_) {                                         \
      int row_ = (threadIdx.x >> 4) + it_ * 16;                                 \
      short8 v_ = *(const short8*)&(lds2)[row_ * 128 +                          \
                      (((threadIdx.x & 15) * 8) ^ ((row_ & 7) << 3))];          \
      *(short8*)((gbase) + (size_t)row_ * (pitch) + (threadIdx.x & 15) * 8) = v_;\
    }                                                                           \
  } while (0)

// ---------------------------------------------------------------- cvt weights
__global__ __launch_bounds__(256) void cvt_w_kernel(
    const float* __restrict__ wk, const float* __restrict__ wq,
    const float* __restrict__ wv, const float* __restrict__ wo,
    short* __restrict__ o) {
  int z = blockIdx.y;
  const float* s = (z == 0) ? wk : (z == 1) ? wq : (z == 2) ? wv : wo;
  int i = blockIdx.x * 256 + threadIdx.x;
  float4 f = ((const float4*)s)[i];
  short4v v;
  v[0] = (short)f2bf(f.x); v[1] = (short)f2bf(f.y);
  v[2] = (short)f2bf(f.z); v[3] = (short)f2bf(f.w);
  if (z < 3) {
    *(short4v*)(o + z * 262144 + i * 4) = v;
  } else {                       // Wo duplicated along K: wdup[co][1024]
    int idx = i * 4, co = idx >> 9, cc = idx & 511;
    short* base = o + 786432 + co * 1024 + cc;
    *(short4v*)base = v;
    *(short4v*)(base + 512) = v;
  }
}

// --------------------------------------------------- transpose inp -> x_t bf16
__global__ __launch_bounds__(256) void transpose_x_kernel(
    const float* __restrict__ inp, short* __restrict__ xt) {
  __shared__ float t[32][33];
  int tx = threadIdx.x, ty = threadIdx.y;
  int n0 = blockIdx.x * 32, c0 = blockIdx.y * 32, b = blockIdx.z;
  const float* src = inp + ((size_t)(b * 512 + c0)) * 4096 + n0;
#pragma unroll
  for (int r = 0; r < 4; ++r) t[ty + r * 8][tx] = src[(ty + r * 8) * 4096 + tx];
  __syncthreads();
  short* dst = xt + ((size_t)((b << 12) + n0)) * 512 + c0;
#pragma unroll
  for (int r = 0; r < 4; ++r) dst[(ty + r * 8) * 512 + tx] = (short)f2bf(t[tx][ty + r * 8]);
}

// ------------------------------------------------------------- QKV projection
__global__ __launch_bounds__(256) void gemm_kqv_kernel(
    const short* __restrict__ xt,
    const short* __restrict__ wk, const short* __restrict__ wq, const short* __restrict__ wv,
    const float* __restrict__ bk, const float* __restrict__ bq, const float* __restrict__ bv,
    short* __restrict__ kt, short* __restrict__ qt, short* __restrict__ vc) {
  const int z = blockIdx.z;
  __shared__ short lds[2 * 128 * 32];
  __shared__ short lds2[128 * 128];
  const short *A, *B;
  int arow0, brow0;
  if (z < 2) { arow0 = blockIdx.x * 128; brow0 = blockIdx.y * 128;
               A = xt + (size_t)arow0 * 512; B = ((z == 0) ? wk : wq) + (size_t)brow0 * 512; }
  else       { arow0 = blockIdx.y * 128; brow0 = blockIdx.x * 128;
               A = wv + (size_t)arow0 * 512; B = xt + (size_t)brow0 * 512; }
  f32x4 acc[4][4] = {};
  gemm_core(A, 512, B, 512, 16, lds, acc);
  const int tid = threadIdx.x, w = tid >> 6, lane = tid & 63;
  const int g = lane >> 4, l15 = lane & 15;
  const int wr = w >> 1, wc = w & 1;
#pragma unroll
  for (int m = 0; m < 4; ++m)
#pragma unroll
    for (int n = 0; n < 4; ++n)
#pragma unroll
      for (int r = 0; r < 4; ++r) {
        int row = wr * 64 + m * 16 + g * 4 + r, col = wc * 64 + n * 16 + l15;
        float v = acc[m][n][r], val;
        if (z == 0)      val = (v + bk[brow0 + col]) * QSCALE;
        else if (z == 1) val = v + bq[brow0 + col];
        else             val = v + bv[arow0 + row];
        BOUNCE_WRITE(lds2, row, col, (short)f2bf(val));
      }
  short* gbase; int pitch;
  if (z == 0)      { gbase = kt + (size_t)arow0 * 512 + brow0; pitch = 512; }
  else if (z == 1) { gbase = qt + (size_t)arow0 * 512 + brow0; pitch = 512; }
  else             { gbase = vc + (size_t)arow0 * 16384 + brow0; pitch = 16384; }
  BOUNCE_FLUSH(lds2, gbase, pitch);
}

// ------------------------------------------------- S-GEMM + exp2 + row-partials
// z = (b, h): P_h[b][i][jl 0..2047] = exp2(kt.qt^T); Lpart[b][jp][i] partial sums
__global__ __launch_bounds__(256) void gemm_s_kernel(
    const short* __restrict__ kt, const short* __restrict__ qt,
    short* __restrict__ P, float* __restrict__ Lpart) {
  __shared__ short lds[2 * 128 * 32];
  __shared__ short lds2[128 * 128];
  const int b = blockIdx.z & 3, h = blockIdx.z >> 2;
  const int i0 = blockIdx.y * 128, jl0 = blockIdx.x * 128;
  const int jg0 = h * 2048 + jl0;
  const short* A = kt + ((size_t)(b << 12) + i0) * 512;
  const short* B = qt + ((size_t)(b << 12) + jg0) * 512;
  f32x4 acc[4][4] = {};
  gemm_core(A, 512, B, 512, 16, lds, acc);
  const int tid = threadIdx.x, w = tid >> 6, lane = tid & 63;
  const int g = lane >> 4, l15 = lane & 15;
  const int wr = w >> 1, wc = w & 1;
  float rs[4][4];
#pragma unroll
  for (int m = 0; m < 4; ++m)
#pragma unroll
    for (int r = 0; r < 4; ++r) rs[m][r] = 0.f;
#pragma unroll
  for (int m = 0; m < 4; ++m)
#pragma unroll
    for (int n = 0; n < 4; ++n)
#pragma unroll
      for (int r = 0; r < 4; ++r) {
        float p = exp2f(acc[m][n][r]);
        rs[m][r] += p;
        int row = wr * 64 + m * 16 + g * 4 + r, col = wc * 64 + n * 16 + l15;
        BOUNCE_WRITE(lds2, row, col, (short)f2bf(p));
      }
  const int jp = (jg0 >> 6) + wc;
  float* Lp = Lpart + (((size_t)b * 64 + jp) << 12) + i0 + wr * 64;
#pragma unroll
  for (int m = 0; m < 4; ++m)
#pragma unroll
    for (int r = 0; r < 4; ++r) {
      float s = rs[m][r];
      s += __shfl_xor(s, 1); s += __shfl_xor(s, 2);
      s += __shfl_xor(s, 4); s += __shfl_xor(s, 8);
      if (l15 == 0) Lp[m * 16 + g * 4 + r] = s;
    }
  short* gbase = P + (size_t)h * 33554432 + ((size_t)((b << 12) + i0)) * 2048 + jl0;
  BOUNCE_FLUSH(lds2, gbase, 2048);
}

// ------------------------------------------------------------------ PV-GEMM
// 1024 blocks, XCD-grouped: 4 c-siblings of one P panel land on one XCD.
// otab[(b,i)][h*512 + c] = bf16 partial P_h . V
__global__ __launch_bounds__(256) void gemm_pv_kernel(
    const short* __restrict__ P, const short* __restrict__ vc,
    short* __restrict__ otab) {
  __shared__ short lds[2 * 128 * 32];
  __shared__ short lds2[128 * 128];
  const int bid = blockIdx.x;
  const int xcd = bid & 7, s = bid >> 3;
  const int c = s & 3, gi = (s >> 2) * 8 + xcd;       // group id 0..255
  const int i = gi & 31, bh = gi >> 5;
  const int b = bh & 3, h = bh >> 2;
  const int i0 = i * 128, c0 = c * 128;
  const short* A = P + (size_t)h * 33554432 + ((size_t)((b << 12) + i0)) * 2048;
  const short* B = vc + (size_t)c0 * 16384 + (b << 12) + h * 2048;
  f32x4 acc[4][4] = {};
  gemm_core(A, 2048, B, 16384, 64, lds, acc);
  const int tid = threadIdx.x, w = tid >> 6, lane = tid & 63;
  const int g = lane >> 4, l15 = lane & 15;
  const int wr = w >> 1, wc = w & 1;
#pragma unroll
  for (int m = 0; m < 4; ++m)
#pragma unroll
    for (int n = 0; n < 4; ++n)
#pragma unroll
      for (int r = 0; r < 4; ++r) {
        int row = wr * 64 + m * 16 + g * 4 + r, col = wc * 64 + n * 16 + l15;
        BOUNCE_WRITE(lds2, row, col, (short)f2bf(acc[m][n][r]));
      }
  short* gbase = otab + ((size_t)((b << 12) + i0)) * 1024 + h * 512 + c0;
  BOUNCE_FLUSH(lds2, gbase, 1024);
}

// ------------------------------------------------------------------ l reduce
__global__ __launch_bounds__(256) void lred_kernel(
    const float* __restrict__ Lpart, float* __restrict__ linv) {
  int i = blockIdx.x * 256 + threadIdx.x;      // 16384 = (b,i)
  int b = i >> 12;
  float s = 0.f;
#pragma unroll 8
  for (int jp = 0; jp < 64; ++jp) s += Lpart[(((size_t)b * 64 + jp) << 12) + (i & 4095)];
  linv[i] = 1.0f / s;
}

// ------------------------------------------------------------ final projection
// out[b][co][n] = (Wo_dup . otab^T)(K=1024) * linv[(b,n)] + bo
__global__ __launch_bounds__(256) void gemm_out_kernel(
    const short* __restrict__ wdup, const short* __restrict__ otab,
    const float* __restrict__ bo, const float* __restrict__ linv,
    float* __restrict__ out) {
  __shared__ short lds[2 * 128 * 32];
  const int b = blockIdx.z;
  const int arow0 = blockIdx.y * 128;                 // co
  const int bn0 = blockIdx.x * 128;                   // n within batch
  const short* A = wdup + (size_t)arow0 * 1024;
  const short* B = otab + ((size_t)((b << 12) + bn0)) * 1024;
  f32x4 acc[4][4] = {};
  gemm_core(A, 1024, B, 1024, 32, lds, acc);
  const int tid = threadIdx.x, w = tid >> 6, lane = tid & 63;
  const int g = lane >> 4, l15 = lane & 15;
  const int wr = w >> 1, wc = w & 1;
#pragma unroll
  for (int m = 0; m < 4; ++m) {
    int co = arow0 + wr * 64 + m * 16 + g * 4;
#pragma unroll
    for (int n = 0; n < 4; ++n) {
      int nl = bn0 + wc * 64 + n * 16 + l15;
      float li = linv[(b << 12) + nl];
#pragma unroll
      for (int r = 0; r < 4; ++r)
        out[((size_t)(b * 512 + co + r) << 12) + nl] = acc[m][n][r] * li + bo[co + r];
    }
  }
}

// ---------------------------------------------------------------------- host
extern "C" void kernel_launch(void* const* d_in, const int* in_sizes, int n_in,
                              void* d_out, int out_size, void* d_ws, size_t ws_size,
                              hipStream_t stream) {
  const float* inp = (const float*)d_in[0];
  const float* Wk = (const float*)d_in[1];
  const float* bk = (const float*)d_in[2];
  const float* Wq = (const float*)d_in[3];
  const float* bq = (const float*)d_in[4];
  const float* Wv = (const float*)d_in[5];
  const float* bv = (const float*)d_in[6];
  const float* Wo = (const float*)d_in[7];
  const float* bo = (const float*)d_in[8];
  float* out = (float*)d_out;
  char* ws = (char*)d_ws;
  const size_t MB = 1048576;
  // layout (227 MB):
  //   kt 0..16 | qt 16..32 | vc 32..48 | wb 48..51 (wk,wq,wv,wdup)
  //   xt 51..67 (dead after kqv; Lpart 51..55 + linv 55..55.07 alias it)
  //   P 67..195 (two 64MB j-half chunks) | otab 195..227
  short* kt    = (short*)(ws);
  short* qt    = (short*)(ws + 16 * MB);
  short* vc    = (short*)(ws + 32 * MB);
  short* wb    = (short*)(ws + 48 * MB);
  short* xt    = (short*)(ws + 51 * MB);
  float* Lpart = (float*)(ws + 51 * MB);
  float* linv  = (float*)(ws + 55 * MB);
  short* P     = (short*)(ws + 67 * MB);
  short* otab  = (short*)(ws + 195 * MB);

  (void)in_sizes; (void)n_in; (void)out_size; (void)ws_size;

  cvt_w_kernel<<<dim3(256, 4), 256, 0, stream>>>(Wk, Wq, Wv, Wo, wb);
  transpose_x_kernel<<<dim3(128, 16, 4), dim3(32, 8, 1), 0, stream>>>(inp, xt);
  gemm_kqv_kernel<<<dim3(128, 4, 3), 256, 0, stream>>>(
      xt, wb, wb + 262144, wb + 524288, bk, bq, bv, kt, qt, vc);
  gemm_s_kernel<<<dim3(16, 32, 8), 256, 0, stream>>>(kt, qt, P, Lpart);
  gemm_pv_kernel<<<dim3(1024), 256, 0, stream>>>(P, vc, otab);
  lred_kernel<<<64, 256, 0, stream>>>(Lpart, linv);
  gemm_out_kernel<<<dim3(32, 4, 4), 256, 0, stream>>>(wb + 786432, otab, bo, linv, out);
}

// Round 4
// 274.833 us; speedup vs baseline: 1.7626x; 1.1560x over previous
//
#include <hip/hip_runtime.h>
#include <hip/hip_bf16.h>

// AttnBlock2D decoupled-GEMM pipeline, R4. B=4, C=512, N=4096 per batch.
//   kt[(b,i)][c] = (x.Wk + bk) * (log2e/sqrt(512))
//   qt[(b,j)][c] = x.Wq + bq
//   vc[c][(b,j)] = x.Wv + bv
//   P_h[b][i][jl] = exp2(kt.qt^T)   (unnormalized), Lpart row partials
//   otab[(b,i)][h*512+c] = P_h.V    (bf16 partial halves side by side)
//   out[b][co][n] = (Wo_dup . otab^T)(K=1024) * linv + bo
// S and PV use a 256^2/BK=64/8-wave deep-pipelined core (T2+T3+T4+T5);
// small GEMMs keep the 128^2 core.

typedef __attribute__((ext_vector_type(4))) float f32x4;
typedef __attribute__((ext_vector_type(8))) short short8;
typedef __attribute__((ext_vector_type(4))) short short4v;

#define QSCALE 0.06376639774f   // (1/sqrt(512)) * log2(e)
#define FENCE asm volatile("" ::: "memory")
#define SBAR  __builtin_amdgcn_s_barrier()

__device__ __forceinline__ unsigned short f2bf(float f) {
  unsigned u = __builtin_bit_cast(unsigned, f);
  unsigned r = (u + 0x7FFFu + ((u >> 16) & 1u)) >> 16;   // RNE
  return (unsigned short)r;
}

__device__ __forceinline__ void gll16(const void* g, void* l) {
  __builtin_amdgcn_global_load_lds((const __attribute__((address_space(1))) void*)g,
                                   (__attribute__((address_space(3))) void*)l, 16, 0, 0);
}

// ==================== 256^2 deep-pipelined core (8 waves, BK=64) ====================
// C[256x256] = A[256xK] . B[256xK]^T. LDS 128KB: A slots [4x16KB] | B slots [4x16KB],
// slot = (buf<<1)|half, half = 128 rows x 64 k (rows 128B, XOR-swizzled (row&7)<<4).
// Counted vmcnt(8): one K-tile (8 loads/thread) always in flight.
#define MFMA_BF16(d, va, vb) \
  d = __builtin_amdgcn_mfma_f32_16x16x32_bf16(va, vb, d, 0, 0, 0)

__device__ __forceinline__ void gemm256_core(
    const short* __restrict__ A, int lda,
    const short* __restrict__ B, int ldb,
    int nkt, char* sm, f32x4 (&acc)[8][4]) {
  const int tid = threadIdx.x, w = tid >> 6, lane = tid & 63;
  const int g = lane >> 4, l15 = lane & 15;
  const int wm = w >> 2, wn = w & 3;
  const int swz = (l15 & 7) << 4;
  const int brow = (wn & 1) << 6;

  auto stageA = [&](int buf, int h, int kt) {
    char* dst = sm + (((buf << 1) | h) << 14) + (w << 10);
    const char* gs = (const char*)A + ((size_t)(h * 128) * lda + (size_t)kt * 64) * 2;
#pragma unroll
    for (int q = 0; q < 2; ++q) {
      int o = (q << 13) | (w << 10) | (lane << 4);
      int row = o >> 7, cb = (o & 127) ^ ((row & 7) << 4);
      gll16(gs + (size_t)row * (lda * 2) + cb, dst + (q << 13));
    }
  };
  auto stageB = [&](int buf, int h, int kt) {
    char* dst = sm + 65536 + (((buf << 1) | h) << 14) + (w << 10);
    const char* gs = (const char*)B + ((size_t)(h * 128) * ldb + (size_t)kt * 64) * 2;
#pragma unroll
    for (int q = 0; q < 2; ++q) {
      int o = (q << 13) | (w << 10) | (lane << 4);
      int row = o >> 7, cb = (o & 127) ^ ((row & 7) << 4);
      gll16(gs + (size_t)row * (ldb * 2) + cb, dst + (q << 13));
    }
  };

  // prologue: stage tiles 0 and 1
  stageA(0, 0, 0); stageA(0, 1, 0); stageB(0, 0, 0); stageB(0, 1, 0);
  stageA(1, 0, 1); stageA(1, 1, 1); stageB(1, 0, 1); stageB(1, 1, 1);
  asm volatile("s_waitcnt vmcnt(8)" ::: "memory");   // tile 0 landed
  SBAR; FENCE;

  for (int t = 0; t < nkt; ++t) {
    const int buf = t & 1;
    const char* SA = sm + (((buf << 1) | wm) << 14);
    const char* SB = sm + 65536 + (((buf << 1) | (wn >> 1)) << 14);
    short8 a[8][2], b[4][2];
    // P0: ds_read k0
#pragma unroll
    for (int mf = 0; mf < 8; ++mf)
      a[mf][0] = *(const short8*)(SA + (mf * 16 + l15) * 128 + ((g * 16) ^ swz));
#pragma unroll
    for (int nf = 0; nf < 4; ++nf)
      b[nf][0] = *(const short8*)(SB + (brow + nf * 16 + l15) * 128 + ((g * 16) ^ swz));
    // P1: ds_read k1 + MFMA k0 mf0-3
#pragma unroll
    for (int mf = 0; mf < 8; ++mf)
      a[mf][1] = *(const short8*)(SA + (mf * 16 + l15) * 128 + ((64 + g * 16) ^ swz));
#pragma unroll
    for (int nf = 0; nf < 4; ++nf)
      b[nf][1] = *(const short8*)(SB + (brow + nf * 16 + l15) * 128 + ((64 + g * 16) ^ swz));
    __builtin_amdgcn_s_setprio(1);
#pragma unroll
    for (int mf = 0; mf < 4; ++mf)
#pragma unroll
      for (int nf = 0; nf < 4; ++nf)
        MFMA_BF16(acc[mf][nf], a[mf][0], b[nf][0]);
    __builtin_amdgcn_s_setprio(0);
    asm volatile("s_waitcnt lgkmcnt(0)" ::: "memory"); // all reads of tile t done
    SBAR; FENCE;                                       // slots of buf now reusable
    // P2: stage A halves of t+2 + MFMA k0 mf4-7
    if (t + 2 < nkt) { stageA(buf, 0, t + 2); stageA(buf, 1, t + 2); }
    __builtin_amdgcn_s_setprio(1);
#pragma unroll
    for (int mf = 4; mf < 8; ++mf)
#pragma unroll
      for (int nf = 0; nf < 4; ++nf)
        MFMA_BF16(acc[mf][nf], a[mf][0], b[nf][0]);
    __builtin_amdgcn_s_setprio(0);
    // P3: stage B halves of t+2 + MFMA k1 mf0-3
    if (t + 2 < nkt) { stageB(buf, 0, t + 2); stageB(buf, 1, t + 2); }
    __builtin_amdgcn_s_setprio(1);
#pragma unroll
    for (int mf = 0; mf < 4; ++mf)
#pragma unroll
      for (int nf = 0; nf < 4; ++nf)
        MFMA_BF16(acc[mf][nf], a[mf][1], b[nf][1]);
    // P4: MFMA k1 mf4-7
#pragma unroll
    for (int mf = 4; mf < 8; ++mf)
#pragma unroll
      for (int nf = 0; nf < 4; ++nf)
        MFMA_BF16(acc[mf][nf], a[mf][1], b[nf][1]);
    __builtin_amdgcn_s_setprio(0);
    if (t + 2 < nkt)      asm volatile("s_waitcnt vmcnt(8)" ::: "memory");
    else if (t + 1 < nkt) asm volatile("s_waitcnt vmcnt(0)" ::: "memory");
    SBAR; FENCE;
  }
}

// 256-tile bounce flush: sm holds 256 rows x 512B (swizzled); 16B coalesced stores.
#define BOUNCE256_WRITE(smp, row, colb, val) \
  *(short*)((smp) + (row) * 512 + (((colb)) ^ (((row) & 7) << 4))) = (val)

__device__ __forceinline__ void bounce256_flush(const char* smp, short* gbase,
                                                int pitch /*shorts*/) {
  const int tid = threadIdx.x;
  SBAR; FENCE;
#pragma unroll
  for (int it = 0; it < 16; ++it) {
    int row = (tid >> 5) + it * 16;
    short8 v = *(const short8*)(smp + row * 512 + (((tid & 31) * 16) ^ ((row & 7) << 4)));
    *(short8*)(gbase + (size_t)row * pitch + (tid & 31) * 8) = v;
  }
}

// ==================== 128^2 core (kqv / out) ====================
__device__ __forceinline__ void gemm_core(const short* __restrict__ A, int lda,
                                          const short* __restrict__ B, int ldb,
                                          int nk, short* lds, f32x4 (&acc)[4][4]) {
  const int tid = threadIdx.x, w = tid >> 6, lane = tid & 63;
  const int g = lane >> 4, l15 = lane & 15;
  const int wr = w >> 1, wc = w & 1;
  const int rsub = lane >> 2, slot = lane & 3;
  char* la = (char*)lds;
  char* lb = (char*)(lds + 128 * 32);
  for (int ki = 0; ki < nk; ++ki) {
    const int k0 = ki * 32;
    __syncthreads();
#pragma unroll
    for (int q = 0; q < 2; ++q) {
      int qq = w * 2 + q;
      int row = qq * 16 + rsub;
      int soff = ((slot ^ (row & 3)) * 16);
      gll16((const char*)(A + (size_t)row * lda + k0) + soff, la + qq * 1024);
      gll16((const char*)(B + (size_t)row * ldb + k0) + soff, lb + qq * 1024);
    }
    __syncthreads();
    short8 am[4], bn[4];
#pragma unroll
    for (int m = 0; m < 4; ++m) {
      int row = wr * 64 + m * 16 + l15;
      am[m] = *(const short8*)(la + row * 64 + ((g * 16) ^ ((l15 & 3) << 4)));
    }
#pragma unroll
    for (int n = 0; n < 4; ++n) {
      int row = wc * 64 + n * 16 + l15;
      bn[n] = *(const short8*)(lb + row * 64 + ((g * 16) ^ ((l15 & 3) << 4)));
    }
#pragma unroll
    for (int m = 0; m < 4; ++m)
#pragma unroll
      for (int n = 0; n < 4; ++n)
        MFMA_BF16(acc[m][n], am[m], bn[n]);
  }
}

#define BOUNCE_WRITE(lds2, row, col, val) \
  (lds2)[(row) * 128 + ((col) ^ (((row) & 7) << 3))] = (val)

#define BOUNCE_FLUSH(lds2, gbase, pitch)                                        \
  do {                                                                          \
    __syncthreads();                                                            \
    _Pragma("unroll")                                                           \
    for (int it_ = 0; it_ < 8; ++it_) {                                         \
      int row_ = (threadIdx.x >> 4) + it_ * 16;                                 \
      short8 v_ = *(const short8*)&(lds2)[row_ * 128 +                          \
                      (((threadIdx.x & 15) * 8) ^ ((row_ & 7) << 3))];          \
      *(short8*)((gbase) + (size_t)row_ * (pitch) + (threadIdx.x & 15) * 8) = v_;\
    }                                                                           \
  } while (0)

// ---------------------------------------------------------------- cvt weights
__global__ __launch_bounds__(256) void cvt_w_kernel(
    const float* __restrict__ wk, const float* __restrict__ wq,
    const float* __restrict__ wv, const float* __restrict__ wo,
    short* __restrict__ o) {
  int z = blockIdx.y;
  const float* s = (z == 0) ? wk : (z == 1) ? wq : (z == 2) ? wv : wo;
  int i = blockIdx.x * 256 + threadIdx.x;
  float4 f = ((const float4*)s)[i];
  short4v v;
  v[0] = (short)f2bf(f.x); v[1] = (short)f2bf(f.y);
  v[2] = (short)f2bf(f.z); v[3] = (short)f2bf(f.w);
  if (z < 3) {
    *(short4v*)(o + z * 262144 + i * 4) = v;
  } else {                       // Wo duplicated along K: wdup[co][1024]
    int idx = i * 4, co = idx >> 9, cc = idx & 511;
    short* base = o + 786432 + co * 1024 + cc;
    *(short4v*)base = v;
    *(short4v*)(base + 512) = v;
  }
}

// --------------------------------------------------- transpose inp -> x_t bf16
__global__ __launch_bounds__(256) void transpose_x_kernel(
    const float* __restrict__ inp, short* __restrict__ xt) {
  __shared__ float t[32][33];
  int tx = threadIdx.x, ty = threadIdx.y;
  int n0 = blockIdx.x * 32, c0 = blockIdx.y * 32, b = blockIdx.z;
  const float* src = inp + ((size_t)(b * 512 + c0)) * 4096 + n0;
#pragma unroll
  for (int r = 0; r < 4; ++r) t[ty + r * 8][tx] = src[(ty + r * 8) * 4096 + tx];
  __syncthreads();
  short* dst = xt + ((size_t)((b << 12) + n0)) * 512 + c0;
#pragma unroll
  for (int r = 0; r < 4; ++r) dst[(ty + r * 8) * 512 + tx] = (short)f2bf(t[tx][ty + r * 8]);
}

// ------------------------------------------------------------- QKV projection
__global__ __launch_bounds__(256) void gemm_kqv_kernel(
    const short* __restrict__ xt,
    const short* __restrict__ wk, const short* __restrict__ wq, const short* __restrict__ wv,
    const float* __restrict__ bk, const float* __restrict__ bq, const float* __restrict__ bv,
    short* __restrict__ kt, short* __restrict__ qt, short* __restrict__ vc) {
  const int z = blockIdx.z;
  __shared__ char smk[32768];          // staging 16KB aliases bounce 32KB
  short* lds = (short*)smk;
  short* lds2 = (short*)smk;
  const short *A, *B;
  int arow0, brow0;
  if (z < 2) { arow0 = blockIdx.x * 128; brow0 = blockIdx.y * 128;
               A = xt + (size_t)arow0 * 512; B = ((z == 0) ? wk : wq) + (size_t)brow0 * 512; }
  else       { arow0 = blockIdx.y * 128; brow0 = blockIdx.x * 128;
               A = wv + (size_t)arow0 * 512; B = xt + (size_t)brow0 * 512; }
  f32x4 acc[4][4] = {};
  gemm_core(A, 512, B, 512, 16, lds, acc);
  const int tid = threadIdx.x, w = tid >> 6, lane = tid & 63;
  const int g = lane >> 4, l15 = lane & 15;
  const int wr = w >> 1, wc = w & 1;
  __syncthreads();                     // staging reads done before bounce overwrite
#pragma unroll
  for (int m = 0; m < 4; ++m)
#pragma unroll
    for (int n = 0; n < 4; ++n)
#pragma unroll
      for (int r = 0; r < 4; ++r) {
        int row = wr * 64 + m * 16 + g * 4 + r, col = wc * 64 + n * 16 + l15;
        float v = acc[m][n][r], val;
        if (z == 0)      val = (v + bk[brow0 + col]) * QSCALE;
        else if (z == 1) val = v + bq[brow0 + col];
        else             val = v + bv[arow0 + row];
        BOUNCE_WRITE(lds2, row, col, (short)f2bf(val));
      }
  short* gbase; int pitch;
  if (z == 0)      { gbase = kt + (size_t)arow0 * 512 + brow0; pitch = 512; }
  else if (z == 1) { gbase = qt + (size_t)arow0 * 512 + brow0; pitch = 512; }
  else             { gbase = vc + (size_t)arow0 * 16384 + brow0; pitch = 16384; }
  BOUNCE_FLUSH(lds2, gbase, pitch);
}

// ---------------------------------------- S-GEMM 256^2 + exp2 + row partials
// grid (8 j, 16 i, 8 (b,h)); P_h[b][i][jl] = exp2(S); Lpart 64-col partials
__global__ __launch_bounds__(512, 2) void gemm_s256_kernel(
    const short* __restrict__ kt, const short* __restrict__ qt,
    short* __restrict__ P, float* __restrict__ Lpart) {
  extern __shared__ char sm[];
  const int b = blockIdx.z & 3, h = blockIdx.z >> 2;
  const int i0 = blockIdx.y * 256, jt0 = blockIdx.x * 256;
  const short* A = kt + ((size_t)(b << 12) + i0) * 512;
  const short* B = qt + ((size_t)((b << 12) + h * 2048 + jt0)) * 512;
  f32x4 acc[8][4] = {};
  gemm256_core(A, 512, B, 512, 8, sm, acc);
  const int tid = threadIdx.x, w = tid >> 6, lane = tid & 63;
  const int g = lane >> 4, l15 = lane & 15;
  const int wm = w >> 2, wn = w & 3;
  const int jp = (h * 2048 + jt0 + wn * 64) >> 6;
  float* Lp = Lpart + (((size_t)b * 64 + jp) << 12) + i0 + wm * 128;
#pragma unroll
  for (int mf = 0; mf < 8; ++mf) {
    float psum[4] = {0.f, 0.f, 0.f, 0.f};
#pragma unroll
    for (int nf = 0; nf < 4; ++nf)
#pragma unroll
      for (int r = 0; r < 4; ++r) {
        float p = exp2f(acc[mf][nf][r]);
        psum[r] += p;
        int row = wm * 128 + mf * 16 + g * 4 + r;
        int colb = (wn * 64 + nf * 16 + l15) * 2;
        BOUNCE256_WRITE(sm, row, colb, (short)f2bf(p));
      }
#pragma unroll
    for (int r = 0; r < 4; ++r) {
      float s = psum[r];
      s += __shfl_xor(s, 1); s += __shfl_xor(s, 2);
      s += __shfl_xor(s, 4); s += __shfl_xor(s, 8);
      if (l15 == 0) Lp[mf * 16 + g * 4 + r] = s;
    }
  }
  short* gbase = P + (size_t)h * 33554432 + ((size_t)((b << 12) + i0)) * 2048 + jt0;
  bounce256_flush(sm, gbase, 2048);
}

// --------------------------------------------------------- PV-GEMM 256^2
// grid (2 c, 16 i, 8 (b,h)); otab[(b,i)][h*512+c] = P_h . V
__global__ __launch_bounds__(512, 2) void gemm_pv256_kernel(
    const short* __restrict__ P, const short* __restrict__ vc,
    short* __restrict__ otab) {
  extern __shared__ char sm[];
  const int b = blockIdx.z & 3, h = blockIdx.z >> 2;
  const int i0 = blockIdx.y * 256, c0 = blockIdx.x * 256;
  const short* A = P + (size_t)h * 33554432 + ((size_t)((b << 12) + i0)) * 2048;
  const short* B = vc + (size_t)c0 * 16384 + (b << 12) + h * 2048;
  f32x4 acc[8][4] = {};
  gemm256_core(A, 2048, B, 16384, 32, sm, acc);
  const int tid = threadIdx.x, w = tid >> 6, lane = tid & 63;
  const int g = lane >> 4, l15 = lane & 15;
  const int wm = w >> 2, wn = w & 3;
#pragma unroll
  for (int mf = 0; mf < 8; ++mf)
#pragma unroll
    for (int nf = 0; nf < 4; ++nf)
#pragma unroll
      for (int r = 0; r < 4; ++r) {
        int row = wm * 128 + mf * 16 + g * 4 + r;
        int colb = (wn * 64 + nf * 16 + l15) * 2;
        BOUNCE256_WRITE(sm, row, colb, (short)f2bf(acc[mf][nf][r]));
      }
  short* gbase = otab + ((size_t)((b << 12) + i0)) * 1024 + h * 512 + c0;
  bounce256_flush(sm, gbase, 1024);
}

// ------------------------------------------------------------------ l reduce
__global__ __launch_bounds__(256) void lred_kernel(
    const float* __restrict__ Lpart, float* __restrict__ linv) {
  int i = blockIdx.x * 256 + threadIdx.x;      // 16384 = (b,i)
  int b = i >> 12;
  float s = 0.f;
#pragma unroll 8
  for (int jp = 0; jp < 64; ++jp) s += Lpart[(((size_t)b * 64 + jp) << 12) + (i & 4095)];
  linv[i] = 1.0f / s;
}

// ------------------------------------------------------------ final projection
__global__ __launch_bounds__(256) void gemm_out_kernel(
    const short* __restrict__ wdup, const short* __restrict__ otab,
    const float* __restrict__ bo, const float* __restrict__ linv,
    float* __restrict__ out) {
  __shared__ short lds[2 * 128 * 32];
  const int b = blockIdx.z;
  const int arow0 = blockIdx.y * 128;                 // co
  const int bn0 = blockIdx.x * 128;                   // n within batch
  const short* A = wdup + (size_t)arow0 * 1024;
  const short* B = otab + ((size_t)((b << 12) + bn0)) * 1024;
  f32x4 acc[4][4] = {};
  gemm_core(A, 1024, B, 1024, 32, lds, acc);
  const int tid = threadIdx.x, w = tid >> 6, lane = tid & 63;
  const int g = lane >> 4, l15 = lane & 15;
  const int wr = w >> 1, wc = w & 1;
#pragma unroll
  for (int m = 0; m < 4; ++m) {
    int co = arow0 + wr * 64 + m * 16 + g * 4;
#pragma unroll
    for (int n = 0; n < 4; ++n) {
      int nl = bn0 + wc * 64 + n * 16 + l15;
      float li = linv[(b << 12) + nl];
#pragma unroll
      for (int r = 0; r < 4; ++r)
        out[((size_t)(b * 512 + co + r) << 12) + nl] = acc[m][n][r] * li + bo[co + r];
    }
  }
}

// ---------------------------------------------------------------------- host
extern "C" void kernel_launch(void* const* d_in, const int* in_sizes, int n_in,
                              void* d_out, int out_size, void* d_ws, size_t ws_size,
                              hipStream_t stream) {
  const float* inp = (const float*)d_in[0];
  const float* Wk = (const float*)d_in[1];
  const float* bk = (const float*)d_in[2];
  const float* Wq = (const float*)d_in[3];
  const float* bq = (const float*)d_in[4];
  const float* Wv = (const float*)d_in[5];
  const float* bv = (const float*)d_in[6];
  const float* Wo = (const float*)d_in[7];
  const float* bo = (const float*)d_in[8];
  float* out = (float*)d_out;
  char* ws = (char*)d_ws;
  const size_t MB = 1048576;
  // layout (227 MB): kt 0..16 | qt 16..32 | vc 32..48 | wb 48..51
  //   xt 51..67 (dead after kqv; Lpart/linv alias) | P 67..195 | otab 195..227
  short* kt    = (short*)(ws);
  short* qt    = (short*)(ws + 16 * MB);
  short* vc    = (short*)(ws + 32 * MB);
  short* wb    = (short*)(ws + 48 * MB);
  short* xt    = (short*)(ws + 51 * MB);
  float* Lpart = (float*)(ws + 51 * MB);
  float* linv  = (float*)(ws + 55 * MB);
  short* P     = (short*)(ws + 67 * MB);
  short* otab  = (short*)(ws + 195 * MB);

  (void)in_sizes; (void)n_in; (void)out_size; (void)ws_size;

  hipFuncSetAttribute((const void*)gemm_s256_kernel,
                      hipFuncAttributeMaxDynamicSharedMemorySize, 131072);
  hipFuncSetAttribute((const void*)gemm_pv256_kernel,
                      hipFuncAttributeMaxDynamicSharedMemorySize, 131072);

  cvt_w_kernel<<<dim3(256, 4), 256, 0, stream>>>(Wk, Wq, Wv, Wo, wb);
  transpose_x_kernel<<<dim3(128, 16, 4), dim3(32, 8, 1), 0, stream>>>(inp, xt);
  gemm_kqv_kernel<<<dim3(128, 4, 3), 256, 0, stream>>>(
      xt, wb, wb + 262144, wb + 524288, bk, bq, bv, kt, qt, vc);
  gemm_s256_kernel<<<dim3(8, 16, 8), 512, 131072, stream>>>(kt, qt, P, Lpart);
  gemm_pv256_kernel<<<dim3(2, 16, 8), 512, 131072, stream>>>(P, vc, otab);
  lred_kernel<<<64, 256, 0, stream>>>(Lpart, linv);
  gemm_out_kernel<<<dim3(32, 4, 4), 256, 0, stream>>>(wb + 786432, otab, bo, linv, out);
}

// Round 5
// 273.447 us; speedup vs baseline: 1.7715x; 1.0051x over previous
//
#include <hip/hip_runtime.h>
#include <hip/hip_bf16.h>

// AttnBlock2D decoupled-GEMM pipeline, R5. B=4, C=512, N=4096 per batch.
//   kt[(b,i)][c] = (x.Wk + bk) * (log2e/sqrt(512))
//   qt[(b,j)][c] = x.Wq + bq
//   vc[c][(b,j)] = x.Wv + bv
//   P_h[b][i][jl] = exp2(kt.qt^T)   (unnormalized), Lpart row partials
//   otab[(b,i)][h*512+c] = P_h.V    (bf16 partial halves side by side)
//   out[b][co][n] = (Wo_dup . otab^T)(K=1024) * linv + bo
// R5: XCD-aware 1D grids everywhere (T1) so panel-sharing blocks are
// co-resident on one XCD's L2; kqv ported to the 256^2 deep-pipelined core.

typedef __attribute__((ext_vector_type(4))) float f32x4;
typedef __attribute__((ext_vector_type(8))) short short8;
typedef __attribute__((ext_vector_type(4))) short short4v;

#define QSCALE 0.06376639774f   // (1/sqrt(512)) * log2(e)
#define FENCE asm volatile("" ::: "memory")
#define SBAR  __builtin_amdgcn_s_barrier()

__device__ __forceinline__ unsigned short f2bf(float f) {
  unsigned u = __builtin_bit_cast(unsigned, f);
  unsigned r = (u + 0x7FFFu + ((u >> 16) & 1u)) >> 16;   // RNE
  return (unsigned short)r;
}

__device__ __forceinline__ void gll16(const void* g, void* l) {
  __builtin_amdgcn_global_load_lds((const __attribute__((address_space(1))) void*)g,
                                   (__attribute__((address_space(3))) void*)l, 16, 0, 0);
}

// ==================== 256^2 deep-pipelined core (8 waves, BK=64) ====================
// C[256x256] = A[256xK] . B[256xK]^T. LDS 128KB: A slots [4x16KB] | B slots [4x16KB],
// slot = (buf<<1)|half, half = 128 rows x 64 k (rows 128B, XOR-swizzled (row&7)<<4).
// Counted vmcnt(8): one K-tile (8 loads/thread) always in flight.
#define MFMA_BF16(d, va, vb) \
  d = __builtin_amdgcn_mfma_f32_16x16x32_bf16(va, vb, d, 0, 0, 0)

__device__ __forceinline__ void gemm256_core(
    const short* __restrict__ A, int lda,
    const short* __restrict__ B, int ldb,
    int nkt, char* sm, f32x4 (&acc)[8][4]) {
  const int tid = threadIdx.x, w = tid >> 6, lane = tid & 63;
  const int g = lane >> 4, l15 = lane & 15;
  const int wm = w >> 2, wn = w & 3;
  const int swz = (l15 & 7) << 4;
  const int brow = (wn & 1) << 6;

  auto stageA = [&](int buf, int h, int kt) {
    char* dst = sm + (((buf << 1) | h) << 14) + (w << 10);
    const char* gs = (const char*)A + ((size_t)(h * 128) * lda + (size_t)kt * 64) * 2;
#pragma unroll
    for (int q = 0; q < 2; ++q) {
      int o = (q << 13) | (w << 10) | (lane << 4);
      int row = o >> 7, cb = (o & 127) ^ ((row & 7) << 4);
      gll16(gs + (size_t)row * (lda * 2) + cb, dst + (q << 13));
    }
  };
  auto stageB = [&](int buf, int h, int kt) {
    char* dst = sm + 65536 + (((buf << 1) | h) << 14) + (w << 10);
    const char* gs = (const char*)B + ((size_t)(h * 128) * ldb + (size_t)kt * 64) * 2;
#pragma unroll
    for (int q = 0; q < 2; ++q) {
      int o = (q << 13) | (w << 10) | (lane << 4);
      int row = o >> 7, cb = (o & 127) ^ ((row & 7) << 4);
      gll16(gs + (size_t)row * (ldb * 2) + cb, dst + (q << 13));
    }
  };

  // prologue: stage tiles 0 and 1
  stageA(0, 0, 0); stageA(0, 1, 0); stageB(0, 0, 0); stageB(0, 1, 0);
  stageA(1, 0, 1); stageA(1, 1, 1); stageB(1, 0, 1); stageB(1, 1, 1);
  asm volatile("s_waitcnt vmcnt(8)" ::: "memory");   // tile 0 landed
  SBAR; FENCE;

  for (int t = 0; t < nkt; ++t) {
    const int buf = t & 1;
    const char* SA = sm + (((buf << 1) | wm) << 14);
    const char* SB = sm + 65536 + (((buf << 1) | (wn >> 1)) << 14);
    short8 a[8][2], b[4][2];
    // P0: ds_read k0
#pragma unroll
    for (int mf = 0; mf < 8; ++mf)
      a[mf][0] = *(const short8*)(SA + (mf * 16 + l15) * 128 + ((g * 16) ^ swz));
#pragma unroll
    for (int nf = 0; nf < 4; ++nf)
      b[nf][0] = *(const short8*)(SB + (brow + nf * 16 + l15) * 128 + ((g * 16) ^ swz));
    // P1: ds_read k1 + MFMA k0 mf0-3
#pragma unroll
    for (int mf = 0; mf < 8; ++mf)
      a[mf][1] = *(const short8*)(SA + (mf * 16 + l15) * 128 + ((64 + g * 16) ^ swz));
#pragma unroll
    for (int nf = 0; nf < 4; ++nf)
      b[nf][1] = *(const short8*)(SB + (brow + nf * 16 + l15) * 128 + ((64 + g * 16) ^ swz));
    __builtin_amdgcn_s_setprio(1);
#pragma unroll
    for (int mf = 0; mf < 4; ++mf)
#pragma unroll
      for (int nf = 0; nf < 4; ++nf)
        MFMA_BF16(acc[mf][nf], a[mf][0], b[nf][0]);
    __builtin_amdgcn_s_setprio(0);
    asm volatile("s_waitcnt lgkmcnt(0)" ::: "memory"); // all reads of tile t done
    SBAR; FENCE;                                       // slots of buf now reusable
    // P2: stage A halves of t+2 + MFMA k0 mf4-7
    if (t + 2 < nkt) { stageA(buf, 0, t + 2); stageA(buf, 1, t + 2); }
    __builtin_amdgcn_s_setprio(1);
#pragma unroll
    for (int mf = 4; mf < 8; ++mf)
#pragma unroll
      for (int nf = 0; nf < 4; ++nf)
        MFMA_BF16(acc[mf][nf], a[mf][0], b[nf][0]);
    __builtin_amdgcn_s_setprio(0);
    // P3: stage B halves of t+2 + MFMA k1 mf0-3
    if (t + 2 < nkt) { stageB(buf, 0, t + 2); stageB(buf, 1, t + 2); }
    __builtin_amdgcn_s_setprio(1);
#pragma unroll
    for (int mf = 0; mf < 4; ++mf)
#pragma unroll
      for (int nf = 0; nf < 4; ++nf)
        MFMA_BF16(acc[mf][nf], a[mf][1], b[nf][1]);
    // P4: MFMA k1 mf4-7
#pragma unroll
    for (int mf = 4; mf < 8; ++mf)
#pragma unroll
      for (int nf = 0; nf < 4; ++nf)
        MFMA_BF16(acc[mf][nf], a[mf][1], b[nf][1]);
    __builtin_amdgcn_s_setprio(0);
    if (t + 2 < nkt)      asm volatile("s_waitcnt vmcnt(8)" ::: "memory");
    else if (t + 1 < nkt) asm volatile("s_waitcnt vmcnt(0)" ::: "memory");
    SBAR; FENCE;
  }
}

// 256-tile bounce flush: sm holds 256 rows x 512B (swizzled); 16B coalesced stores.
#define BOUNCE256_WRITE(smp, row, colb, val) \
  *(short*)((smp) + (row) * 512 + (((colb)) ^ (((row) & 7) << 4))) = (val)

__device__ __forceinline__ void bounce256_flush(const char* smp, short* gbase,
                                                int pitch /*shorts*/) {
  const int tid = threadIdx.x;
  SBAR; FENCE;
#pragma unroll
  for (int it = 0; it < 16; ++it) {
    int row = (tid >> 5) + it * 16;
    short8 v = *(const short8*)(smp + row * 512 + (((tid & 31) * 16) ^ ((row & 7) << 4)));
    *(short8*)(gbase + (size_t)row * pitch + (tid & 31) * 8) = v;
  }
}

// ==================== 128^2 core (final projection only) ====================
__device__ __forceinline__ void gemm_core(const short* __restrict__ A, int lda,
                                          const short* __restrict__ B, int ldb,
                                          int nk, short* lds, f32x4 (&acc)[4][4]) {
  const int tid = threadIdx.x, w = tid >> 6, lane = tid & 63;
  const int g = lane >> 4, l15 = lane & 15;
  const int wr = w >> 1, wc = w & 1;
  const int rsub = lane >> 2, slot = lane & 3;
  char* la = (char*)lds;
  char* lb = (char*)(lds + 128 * 32);
  for (int ki = 0; ki < nk; ++ki) {
    const int k0 = ki * 32;
    __syncthreads();
#pragma unroll
    for (int q = 0; q < 2; ++q) {
      int qq = w * 2 + q;
      int row = qq * 16 + rsub;
      int soff = ((slot ^ (row & 3)) * 16);
      gll16((const char*)(A + (size_t)row * lda + k0) + soff, la + qq * 1024);
      gll16((const char*)(B + (size_t)row * ldb + k0) + soff, lb + qq * 1024);
    }
    __syncthreads();
    short8 am[4], bn[4];
#pragma unroll
    for (int m = 0; m < 4; ++m) {
      int row = wr * 64 + m * 16 + l15;
      am[m] = *(const short8*)(la + row * 64 + ((g * 16) ^ ((l15 & 3) << 4)));
    }
#pragma unroll
    for (int n = 0; n < 4; ++n) {
      int row = wc * 64 + n * 16 + l15;
      bn[n] = *(const short8*)(lb + row * 64 + ((g * 16) ^ ((l15 & 3) << 4)));
    }
#pragma unroll
    for (int m = 0; m < 4; ++m)
#pragma unroll
      for (int n = 0; n < 4; ++n)
        MFMA_BF16(acc[m][n], am[m], bn[n]);
  }
}

// ---------------------------------------------------------------- cvt weights
__global__ __launch_bounds__(256) void cvt_w_kernel(
    const float* __restrict__ wk, const float* __restrict__ wq,
    const float* __restrict__ wv, const float* __restrict__ wo,
    short* __restrict__ o) {
  int z = blockIdx.y;
  const float* s = (z == 0) ? wk : (z == 1) ? wq : (z == 2) ? wv : wo;
  int i = blockIdx.x * 256 + threadIdx.x;
  float4 f = ((const float4*)s)[i];
  short4v v;
  v[0] = (short)f2bf(f.x); v[1] = (short)f2bf(f.y);
  v[2] = (short)f2bf(f.z); v[3] = (short)f2bf(f.w);
  if (z < 3) {
    *(short4v*)(o + z * 262144 + i * 4) = v;
  } else {                       // Wo duplicated along K: wdup[co][1024]
    int idx = i * 4, co = idx >> 9, cc = idx & 511;
    short* base = o + 786432 + co * 1024 + cc;
    *(short4v*)base = v;
    *(short4v*)(base + 512) = v;
  }
}

// --------------------------------------------------- transpose inp -> x_t bf16
__global__ __launch_bounds__(256) void transpose_x_kernel(
    const float* __restrict__ inp, short* __restrict__ xt) {
  __shared__ float t[32][33];
  int tx = threadIdx.x, ty = threadIdx.y;
  int n0 = blockIdx.x * 32, c0 = blockIdx.y * 32, b = blockIdx.z;
  const float* src = inp + ((size_t)(b * 512 + c0)) * 4096 + n0;
#pragma unroll
  for (int r = 0; r < 4; ++r) t[ty + r * 8][tx] = src[(ty + r * 8) * 4096 + tx];
  __syncthreads();
  short* dst = xt + ((size_t)((b << 12) + n0)) * 512 + c0;
#pragma unroll
  for (int r = 0; r < 4; ++r) dst[(ty + r * 8) * 512 + tx] = (short)f2bf(t[tx][ty + r * 8]);
}

// ------------------------------------------------- QKV projection (256^2 core)
// 384 blocks 1D. panel = xt 256-row panel (0..63); 6 consumers per panel
// co-located on one XCD: t=0,1: z=0 (kt) y=t&1; t=2,3: z=1 (qt); t=4,5: z=2 (vc).
__global__ __launch_bounds__(512, 2) void kqv256_kernel(
    const short* __restrict__ xt,
    const short* __restrict__ wk, const short* __restrict__ wq, const short* __restrict__ wv,
    const float* __restrict__ bk, const float* __restrict__ bq, const float* __restrict__ bv,
    short* __restrict__ kt, short* __restrict__ qt, short* __restrict__ vc) {
  extern __shared__ char sm[];
  const int bid = blockIdx.x;
  const int xcd = bid & 7, s = bid >> 3;         // s: 0..47
  const int pg = s / 6, t = s % 6;
  const int panel = pg * 8 + xcd;                // 0..63
  const int z = (t < 4) ? (t >> 1) : 2;
  const short *A, *B;
  int arow0, brow0;
  if (z < 2) {
    arow0 = panel * 256; brow0 = (t & 1) * 256;
    A = xt + (size_t)arow0 * 512;
    B = ((z == 0) ? wk : wq) + (size_t)brow0 * 512;
  } else {
    arow0 = (t - 4) * 256; brow0 = panel * 256;
    A = wv + (size_t)arow0 * 512;
    B = xt + (size_t)brow0 * 512;
  }
  f32x4 acc[8][4] = {};
  gemm256_core(A, 512, B, 512, 8, sm, acc);
  const int tid = threadIdx.x, w = tid >> 6, lane = tid & 63;
  const int gq = lane >> 4, l15 = lane & 15;
  const int wm = w >> 2, wn = w & 3;
#pragma unroll
  for (int mf = 0; mf < 8; ++mf)
#pragma unroll
    for (int nf = 0; nf < 4; ++nf)
#pragma unroll
      for (int r = 0; r < 4; ++r) {
        int row = wm * 128 + mf * 16 + gq * 4 + r;
        int col = wn * 64 + nf * 16 + l15;
        float v = acc[mf][nf][r], val;
        if (z == 0)      val = (v + bk[brow0 + col]) * QSCALE;
        else if (z == 1) val = v + bq[brow0 + col];
        else             val = v + bv[arow0 + row];
        BOUNCE256_WRITE(sm, row, col * 2, (short)f2bf(val));
      }
  short* gbase; int pitch;
  if (z == 0)      { gbase = kt + (size_t)arow0 * 512 + brow0; pitch = 512; }
  else if (z == 1) { gbase = qt + (size_t)arow0 * 512 + brow0; pitch = 512; }
  else             { gbase = vc + (size_t)arow0 * 16384 + brow0; pitch = 16384; }
  bounce256_flush(sm, gbase, pitch);
}

// ---------------------------------------- S-GEMM 256^2 + exp2 + row partials
// 1024 blocks 1D. xcd = (b,h); per XCD-round: 4 kt panels + 8 qt panels = 3MB L2.
__global__ __launch_bounds__(512, 2) void gemm_s256_kernel(
    const short* __restrict__ kt, const short* __restrict__ qt,
    short* __restrict__ P, float* __restrict__ Lpart) {
  extern __shared__ char sm[];
  const int bid = blockIdx.x;
  const int xcd = bid & 7, s = bid >> 3;         // s: 0..127
  const int b = xcd >> 1, h = xcd & 1;
  const int jt0 = (s & 7) * 256, i0 = (s >> 3) * 256;
  const short* A = kt + ((size_t)(b << 12) + i0) * 512;
  const short* B = qt + ((size_t)((b << 12) + h * 2048 + jt0)) * 512;
  f32x4 acc[8][4] = {};
  gemm256_core(A, 512, B, 512, 8, sm, acc);
  const int tid = threadIdx.x, w = tid >> 6, lane = tid & 63;
  const int gq = lane >> 4, l15 = lane & 15;
  const int wm = w >> 2, wn = w & 3;
  const int jp = (h * 2048 + jt0 + wn * 64) >> 6;
  float* Lp = Lpart + (((size_t)b * 64 + jp) << 12) + i0 + wm * 128;
#pragma unroll
  for (int mf = 0; mf < 8; ++mf) {
    float psum[4] = {0.f, 0.f, 0.f, 0.f};
#pragma unroll
    for (int nf = 0; nf < 4; ++nf)
#pragma unroll
      for (int r = 0; r < 4; ++r) {
        float p = exp2f(acc[mf][nf][r]);
        psum[r] += p;
        int row = wm * 128 + mf * 16 + gq * 4 + r;
        int colb = (wn * 64 + nf * 16 + l15) * 2;
        BOUNCE256_WRITE(sm, row, colb, (short)f2bf(p));
      }
#pragma unroll
    for (int r = 0; r < 4; ++r) {
      float ss = psum[r];
      ss += __shfl_xor(ss, 1); ss += __shfl_xor(ss, 2);
      ss += __shfl_xor(ss, 4); ss += __shfl_xor(ss, 8);
      if (l15 == 0) Lp[mf * 16 + gq * 4 + r] = ss;
    }
  }
  short* gbase = P + (size_t)h * 33554432 + ((size_t)((b << 12) + i0)) * 2048 + jt0;
  bounce256_flush(sm, gbase, 2048);
}

// --------------------------------------------------------- PV-GEMM 256^2
// 256 blocks 1D. Each XCD owns one (b,h): P panel's 2 c-siblings co-resident.
__global__ __launch_bounds__(512, 2) void gemm_pv256_kernel(
    const short* __restrict__ P, const short* __restrict__ vc,
    short* __restrict__ otab) {
  extern __shared__ char sm[];
  const int bid = blockIdx.x;
  const int xcd = bid & 7, s = bid >> 3;         // s: 0..31
  const int b = xcd >> 1, h = xcd & 1;
  const int c0 = (s & 1) * 256, i0 = (s >> 1) * 256;
  const short* A = P + (size_t)h * 33554432 + ((size_t)((b << 12) + i0)) * 2048;
  const short* B = vc + (size_t)c0 * 16384 + (b << 12) + h * 2048;
  f32x4 acc[8][4] = {};
  gemm256_core(A, 2048, B, 16384, 32, sm, acc);
  const int tid = threadIdx.x, w = tid >> 6, lane = tid & 63;
  const int gq = lane >> 4, l15 = lane & 15;
  const int wm = w >> 2, wn = w & 3;
#pragma unroll
  for (int mf = 0; mf < 8; ++mf)
#pragma unroll
    for (int nf = 0; nf < 4; ++nf)
#pragma unroll
      for (int r = 0; r < 4; ++r) {
        int row = wm * 128 + mf * 16 + gq * 4 + r;
        int colb = (wn * 64 + nf * 16 + l15) * 2;
        BOUNCE256_WRITE(sm, row, colb, (short)f2bf(acc[mf][nf][r]));
      }
  short* gbase = otab + ((size_t)((b << 12) + i0)) * 1024 + h * 512 + c0;
  bounce256_flush(sm, gbase, 1024);
}

// ------------------------------------------------------------------ l reduce
__global__ __launch_bounds__(256) void lred_kernel(
    const float* __restrict__ Lpart, float* __restrict__ linv) {
  int i = blockIdx.x * 256 + threadIdx.x;      // 16384 = (b,i)
  int b = i >> 12;
  float s = 0.f;
#pragma unroll 8
  for (int jp = 0; jp < 64; ++jp) s += Lpart[(((size_t)b * 64 + jp) << 12) + (i & 4095)];
  linv[i] = 1.0f / s;
}

// ------------------------------------------------------------ final projection
// 512 blocks 1D: the 4 co-tiles sharing an otab panel are co-XCD.
__global__ __launch_bounds__(256) void gemm_out_kernel(
    const short* __restrict__ wdup, const short* __restrict__ otab,
    const float* __restrict__ bo, const float* __restrict__ linv,
    float* __restrict__ out) {
  __shared__ short lds[2 * 128 * 32];
  const int bid = blockIdx.x;
  const int xcd = bid & 7, s = bid >> 3;        // s: 0..63
  const int cot = s & 3;
  const int p = (s >> 2) * 8 + xcd;             // 0..127 otab panel
  const int nt = p & 31, b = p >> 5;
  const int arow0 = cot * 128;                  // co
  const int bn0 = nt * 128;                     // n within batch
  const short* A = wdup + (size_t)arow0 * 1024;
  const short* B = otab + ((size_t)((b << 12) + bn0)) * 1024;
  f32x4 acc[4][4] = {};
  gemm_core(A, 1024, B, 1024, 32, lds, acc);
  const int tid = threadIdx.x, w = tid >> 6, lane = tid & 63;
  const int g = lane >> 4, l15 = lane & 15;
  const int wr = w >> 1, wc = w & 1;
#pragma unroll
  for (int m = 0; m < 4; ++m) {
    int co = arow0 + wr * 64 + m * 16 + g * 4;
#pragma unroll
    for (int n = 0; n < 4; ++n) {
      int nl = bn0 + wc * 64 + n * 16 + l15;
      float li = linv[(b << 12) + nl];
#pragma unroll
      for (int r = 0; r < 4; ++r)
        out[((size_t)(b * 512 + co + r) << 12) + nl] = acc[m][n][r] * li + bo[co + r];
    }
  }
}

// ---------------------------------------------------------------------- host
extern "C" void kernel_launch(void* const* d_in, const int* in_sizes, int n_in,
                              void* d_out, int out_size, void* d_ws, size_t ws_size,
                              hipStream_t stream) {
  const float* inp = (const float*)d_in[0];
  const float* Wk = (const float*)d_in[1];
  const float* bk = (const float*)d_in[2];
  const float* Wq = (const float*)d_in[3];
  const float* bq = (const float*)d_in[4];
  const float* Wv = (const float*)d_in[5];
  const float* bv = (const float*)d_in[6];
  const float* Wo = (const float*)d_in[7];
  const float* bo = (const float*)d_in[8];
  float* out = (float*)d_out;
  char* ws = (char*)d_ws;
  const size_t MB = 1048576;
  // layout (227 MB): kt 0..16 | qt 16..32 | vc 32..48 | wb 48..51
  //   xt 51..67 (dead after kqv; Lpart/linv alias) | P 67..195 | otab 195..227
  short* kt    = (short*)(ws);
  short* qt    = (short*)(ws + 16 * MB);
  short* vc    = (short*)(ws + 32 * MB);
  short* wb    = (short*)(ws + 48 * MB);
  short* xt    = (short*)(ws + 51 * MB);
  float* Lpart = (float*)(ws + 51 * MB);
  float* linv  = (float*)(ws + 55 * MB);
  short* P     = (short*)(ws + 67 * MB);
  short* otab  = (short*)(ws + 195 * MB);

  (void)in_sizes; (void)n_in; (void)out_size; (void)ws_size;

  hipFuncSetAttribute((const void*)kqv256_kernel,
                      hipFuncAttributeMaxDynamicSharedMemorySize, 131072);
  hipFuncSetAttribute((const void*)gemm_s256_kernel,
                      hipFuncAttributeMaxDynamicSharedMemorySize, 131072);
  hipFuncSetAttribute((const void*)gemm_pv256_kernel,
                      hipFuncAttributeMaxDynamicSharedMemorySize, 131072);

  cvt_w_kernel<<<dim3(256, 4), 256, 0, stream>>>(Wk, Wq, Wv, Wo, wb);
  transpose_x_kernel<<<dim3(128, 16, 4), dim3(32, 8, 1), 0, stream>>>(inp, xt);
  kqv256_kernel<<<384, 512, 131072, stream>>>(
      xt, wb, wb + 262144, wb + 524288, bk, bq, bv, kt, qt, vc);
  gemm_s256_kernel<<<1024, 512, 131072, stream>>>(kt, qt, P, Lpart);
  gemm_pv256_kernel<<<256, 512, 131072, stream>>>(P, vc, otab);
  lred_kernel<<<64, 256, 0, stream>>>(Lpart, linv);
  gemm_out_kernel<<<512, 256, 0, stream>>>(wb + 786432, otab, bo, linv, out);
}